// Round 2
// baseline (507.052 us; speedup 1.0000x reference)
//
#include <hip/hip_runtime.h>
#include <hip/hip_bf16.h>
#include <stdint.h>

typedef __hip_bfloat16 bf16;
typedef __attribute__((ext_vector_type(8))) short short8;
typedef __attribute__((ext_vector_type(4))) float f32x4;

#define NWIN 1024
#define NH 16
#define HD 32
#define SHIFT 4

// window row r (= win*64 + token) -> source/dest pixel index in (B,64,64) grid.
// Same formula for gather (roll -4) and scatter (roll +4): they are inverses.
__device__ __forceinline__ int row_to_pixel(int r) {
    int win = r >> 6, t = r & 63;
    int b = win >> 6, wy = (win >> 3) & 7, wx = win & 7;
    int h = ((wy << 3) + (t >> 3) + SHIFT) & 63;
    int w = ((wx << 3) + (t & 7) + SHIFT) & 63;
    return (((b << 6) | h) << 6) | w;
}

__device__ __forceinline__ short f2bf_bits(float f) {
    bf16 h = __float2bfloat16(f);
    return *reinterpret_cast<short*>(&h);
}

// fp32 -> bf16 transpose for weights
__global__ void transpose_f2b(const float* __restrict__ src, short* __restrict__ dst,
                              int K, int N) {
    int idx = blockIdx.x * 256 + threadIdx.x;
    if (idx >= K * N) return;
    int k = idx / N, n = idx - k * N;
    dst[n * K + k] = f2bf_bits(src[idx]);
}

// ---------------- pre-pass: gather (cyclic roll + window partition) + fp32->bf16 cast ----------------
// A'[r][k] = bf16(x[row_to_pixel(r)*512 + k]); each thread does 8 contiguous elems.
__global__ __launch_bounds__(256)
void gather_cast(const float* __restrict__ x, short* __restrict__ a) {
    int chunk = blockIdx.x * 256 + threadIdx.x;   // 65536*64 chunks of 8
    int r = chunk >> 6, c8 = (chunk & 63) << 3;
    int pix = row_to_pixel(r);
    const float* src = x + pix * 512 + c8;
    float4 f0 = *(const float4*)src;
    float4 f1 = *(const float4*)(src + 4);
    short8 v;
    v[0] = f2bf_bits(f0.x); v[1] = f2bf_bits(f0.y);
    v[2] = f2bf_bits(f0.z); v[3] = f2bf_bits(f0.w);
    v[4] = f2bf_bits(f1.x); v[5] = f2bf_bits(f1.y);
    v[6] = f2bf_bits(f1.z); v[7] = f2bf_bits(f1.w);
    *(short8*)(a + r * 512 + c8) = v;
}

// ---------------- QKV GEMM: A = pre-gathered bf16 (65536 x 512), B = wqkvT bf16 (1536 x 512) ----------------
// grid = dim3(12, 512): blockIdx.x = n-slab (fastest) so the 12 blocks sharing one
// 128-row A-panel dispatch together -> A fetched once, reused from L2/L3.
__global__ __launch_bounds__(256, 2)
void qkv_gemm(const bf16* __restrict__ a, const bf16* __restrict__ wT,
              const float* __restrict__ bqkv, bf16* __restrict__ qkv) {
    __shared__ __align__(16) short As[128 * 40];
    __shared__ __align__(16) short Bs[128 * 40];
    const int tid = threadIdx.x;
    const int lane = tid & 63, wave = tid >> 6;
    const int wr = wave >> 1, wc = wave & 1;
    const int m0 = blockIdx.y * 128, n0 = blockIdx.x * 128;

    const short* ag[2];
    const short* bg[2];
    int arow[2], ac8[2];
#pragma unroll
    for (int s = 0; s < 2; ++s) {
        int chunk = tid + s * 256;           // 512 chunks of 8 elems (row-major 128x32)
        int row = chunk >> 2, c8 = (chunk & 3) << 3;
        arow[s] = row; ac8[s] = c8;
        ag[s] = (const short*)a + (m0 + row) * 512 + c8;
        bg[s] = (const short*)wT + (n0 + row) * 512 + c8;
    }

    f32x4 acc[4][4] = {};
    for (int k0 = 0; k0 < 512; k0 += 32) {
        __syncthreads();
#pragma unroll
        for (int s = 0; s < 2; ++s) {
            *(short8*)&As[arow[s] * 40 + ac8[s]] = *(const short8*)(ag[s] + k0);
            *(short8*)&Bs[arow[s] * 40 + ac8[s]] = *(const short8*)(bg[s] + k0);
        }
        __syncthreads();
        const int kk = (lane >> 4) << 3;
        short8 af[4], bfr[4];
#pragma unroll
        for (int mt = 0; mt < 4; ++mt)
            af[mt] = *(const short8*)&As[(wr * 64 + mt * 16 + (lane & 15)) * 40 + kk];
#pragma unroll
        for (int nt = 0; nt < 4; ++nt)
            bfr[nt] = *(const short8*)&Bs[(wc * 64 + nt * 16 + (lane & 15)) * 40 + kk];
#pragma unroll
        for (int mt = 0; mt < 4; ++mt)
#pragma unroll
            for (int nt = 0; nt < 4; ++nt)
                acc[mt][nt] = __builtin_amdgcn_mfma_f32_16x16x32_bf16(af[mt], bfr[nt],
                                                                      acc[mt][nt], 0, 0, 0);
    }

    // epilogue: C/D layout col=lane&15, row=(lane>>4)*4+reg [m89]
#pragma unroll
    for (int mt = 0; mt < 4; ++mt) {
        int rbase = m0 + wr * 64 + mt * 16 + ((lane >> 4) << 2);
#pragma unroll
        for (int nt = 0; nt < 4; ++nt) {
            int c = n0 + wc * 64 + nt * 16 + (lane & 15);
            int which = c >> 9, head = (c >> 5) & 15, d = c & 31;
            float bias = bqkv[c];
            float scale = (which == 0) ? 0.17677669529663689f : 1.0f;
#pragma unroll
            for (int reg = 0; reg < 4; ++reg) {
                int r = rbase + reg;
                int win = r >> 6, t = r & 63;
                float v = (acc[mt][nt][reg] + bias) * scale;
                qkv[(((which * NWIN + win) * NH + head) * 64 + t) * HD + d] = __float2bfloat16(v);
            }
        }
    }
}

// ---------------- attention: one block per (window, head) ----------------
__global__ __launch_bounds__(256, 2)
void attn_kernel(bf16* __restrict__ qkv, const float* __restrict__ relpos) {
    const int win = blockIdx.x, head = blockIdx.y;
    __shared__ __align__(16) short qs[64 * 40];
    __shared__ __align__(16) short ks[64 * 40];
    __shared__ __align__(16) short vT[32 * 72];
    __shared__ float Ss[64 * 65];
    __shared__ __align__(16) short Ps[64 * 72];
    __shared__ float rel[225];
    const int tid = threadIdx.x, lane = tid & 63, wave = tid >> 6;
    const int base = (win * NH + head) * 2048;
    const short* qg = (const short*)qkv + base;
    const short* kg = qg + NWIN * NH * 2048;
    const short* vg = kg + NWIN * NH * 2048;

    {
        int row = tid >> 2, c8 = (tid & 3) << 3;
        *(short8*)&qs[row * 40 + c8] = *(const short8*)(qg + row * 32 + c8);
        *(short8*)&ks[row * 40 + c8] = *(const short8*)(kg + row * 32 + c8);
        short8 vv = *(const short8*)(vg + row * 32 + c8);
#pragma unroll
        for (int e = 0; e < 8; ++e) vT[(c8 + e) * 72 + row] = vv[e];
    }
    if (tid < 225) rel[tid] = relpos[tid * 16 + head];   // only this head's column
    __syncthreads();

    // S = q k^T (q pre-scaled); wave handles 16 q-rows x 64 keys
    {
        const int kk = (lane >> 4) << 3;
        short8 aq = *(const short8*)&qs[(wave * 16 + (lane & 15)) * 40 + kk];
        f32x4 sacc[4];
#pragma unroll
        for (int nt = 0; nt < 4; ++nt) {
            short8 bk = *(const short8*)&ks[(nt * 16 + (lane & 15)) * 40 + kk];
            f32x4 z = {};
            sacc[nt] = __builtin_amdgcn_mfma_f32_16x16x32_bf16(aq, bk, z, 0, 0, 0);
        }
#pragma unroll
        for (int nt = 0; nt < 4; ++nt)
#pragma unroll
            for (int reg = 0; reg < 4; ++reg) {
                int qt = wave * 16 + ((lane >> 4) << 2) + reg;
                int kt = nt * 16 + (lane & 15);
                int idx = ((qt >> 3) - (kt >> 3) + 7) * 15 + ((qt & 7) - (kt & 7) + 7);
                Ss[qt * 65 + kt] = sacc[nt][reg] + rel[idx];
            }
    }
    __syncthreads();

    // fp32 softmax: 4 lanes per row, quad shuffle reduce
    {
        int row = tid >> 2, col0 = (tid & 3) << 4;
        float v[16];
        float m = -3e38f;
#pragma unroll
        for (int e = 0; e < 16; ++e) { v[e] = Ss[row * 65 + col0 + e]; m = fmaxf(m, v[e]); }
        m = fmaxf(m, __shfl_xor(m, 1));
        m = fmaxf(m, __shfl_xor(m, 2));
        float s = 0.f;
#pragma unroll
        for (int e = 0; e < 16; ++e) { v[e] = __expf(v[e] - m); s += v[e]; }
        s += __shfl_xor(s, 1);
        s += __shfl_xor(s, 2);
        float inv = 1.f / s;
#pragma unroll
        for (int e = 0; e < 16; ++e) Ps[row * 72 + col0 + e] = f2bf_bits(v[e] * inv);
    }
    __syncthreads();

    // O = P V : wave -> 16 rows x 32 dims, K=64 in 2 steps
    {
        f32x4 oacc[2] = {};
#pragma unroll
        for (int kstep = 0; kstep < 2; ++kstep) {
            const int kk = kstep * 32 + ((lane >> 4) << 3);
            short8 ap = *(const short8*)&Ps[(wave * 16 + (lane & 15)) * 72 + kk];
#pragma unroll
            for (int nt = 0; nt < 2; ++nt) {
                short8 bv = *(const short8*)&vT[(nt * 16 + (lane & 15)) * 72 + kk];
                oacc[nt] = __builtin_amdgcn_mfma_f32_16x16x32_bf16(ap, bv, oacc[nt], 0, 0, 0);
            }
        }
        short* og = (short*)qkv + base;  // overwrite q slice (disjoint per block)
#pragma unroll
        for (int nt = 0; nt < 2; ++nt)
#pragma unroll
            for (int reg = 0; reg < 4; ++reg) {
                int t = wave * 16 + ((lane >> 4) << 2) + reg;
                int d = nt * 16 + (lane & 15);
                og[t * 32 + d] = f2bf_bits(oacc[nt][reg]);
            }
    }
}

// ---------------- out projection GEMM: A = attn out (q slice), scatter fp32 with roll ----------------
// grid = dim3(4, 512): n-slab fastest for A-panel L2 reuse (same as qkv_gemm).
__global__ __launch_bounds__(256, 2)
void out_gemm(const bf16* __restrict__ ain, const bf16* __restrict__ wT,
              const float* __restrict__ bout, float* __restrict__ out) {
    __shared__ __align__(16) short As[128 * 40];
    __shared__ __align__(16) short Bs[128 * 40];
    const int tid = threadIdx.x;
    const int lane = tid & 63, wave = tid >> 6;
    const int wr = wave >> 1, wc = wave & 1;
    const int m0 = blockIdx.y * 128, n0 = blockIdx.x * 128;

    const short* ag[2];
    const short* bg[2];
    int arow[2], ac8[2];
#pragma unroll
    for (int s = 0; s < 2; ++s) {
        int chunk = tid + s * 256;
        int row = chunk >> 2, c8 = (chunk & 3) << 3;
        arow[s] = row; ac8[s] = c8;
        int r = m0 + row, win = r >> 6, t = r & 63;
        // A[r][k]: k = head*32+d -> ain[((win*16+head)*64 + t)*32 + d]; +k0 step = k0*64 elems
        ag[s] = (const short*)ain + win * 32768 + t * 32 + c8;
        bg[s] = (const short*)wT + (n0 + row) * 512 + c8;
    }

    f32x4 acc[4][4] = {};
    for (int k0 = 0; k0 < 512; k0 += 32) {
        __syncthreads();
#pragma unroll
        for (int s = 0; s < 2; ++s) {
            *(short8*)&As[arow[s] * 40 + ac8[s]] = *(const short8*)(ag[s] + k0 * 64);
            *(short8*)&Bs[arow[s] * 40 + ac8[s]] = *(const short8*)(bg[s] + k0);
        }
        __syncthreads();
        const int kk = (lane >> 4) << 3;
        short8 af[4], bfr[4];
#pragma unroll
        for (int mt = 0; mt < 4; ++mt)
            af[mt] = *(const short8*)&As[(wr * 64 + mt * 16 + (lane & 15)) * 40 + kk];
#pragma unroll
        for (int nt = 0; nt < 4; ++nt)
            bfr[nt] = *(const short8*)&Bs[(wc * 64 + nt * 16 + (lane & 15)) * 40 + kk];
#pragma unroll
        for (int mt = 0; mt < 4; ++mt)
#pragma unroll
            for (int nt = 0; nt < 4; ++nt)
                acc[mt][nt] = __builtin_amdgcn_mfma_f32_16x16x32_bf16(af[mt], bfr[nt],
                                                                      acc[mt][nt], 0, 0, 0);
    }

#pragma unroll
    for (int mt = 0; mt < 4; ++mt) {
        int rbase = m0 + wr * 64 + mt * 16 + ((lane >> 4) << 2);
#pragma unroll
        for (int nt = 0; nt < 4; ++nt) {
            int c = n0 + wc * 64 + nt * 16 + (lane & 15);
            float bias = bout[c];
#pragma unroll
            for (int reg = 0; reg < 4; ++reg) {
                int r = rbase + reg;
                int pix = row_to_pixel(r);
                out[pix * 512 + c] = acc[mt][nt][reg] + bias;
            }
        }
    }
}

extern "C" void kernel_launch(void* const* d_in, const int* in_sizes, int n_in,
                              void* d_out, int out_size, void* d_ws, size_t ws_size,
                              hipStream_t stream) {
    const float* x       = (const float*)d_in[0];   // (16,64,64,512) fp32
    const float* w_qkv   = (const float*)d_in[1];   // (512,1536) fp32
    const float* b_qkv   = (const float*)d_in[2];   // (1536,) fp32
    const float* rel_pos = (const float*)d_in[3];   // (225,16) fp32
    const float* w_out   = (const float*)d_in[4];   // (512,512) fp32
    const float* b_out   = (const float*)d_in[5];   // (512,) fp32
    float* out = (float*)d_out;

    bf16* wqkvT  = (bf16*)d_ws;                  // 1536*512 bf16
    bf16* woutT  = wqkvT + 1536 * 512;           // 512*512 bf16
    bf16* qkvbuf = woutT + 512 * 512;            // 3*1024*16*64*32 bf16 (~201 MB)

    // A' (gathered bf16 x, 65536x512 = 67 MB) lives in d_out: it is fully
    // consumed by qkv_gemm before out_gemm overwrites d_out at the end.
    short* agather = (short*)d_out;

    transpose_f2b<<<(512 * 1536 + 255) / 256, 256, 0, stream>>>(
        w_qkv, (short*)wqkvT, 512, 1536);
    transpose_f2b<<<(512 * 512 + 255) / 256, 256, 0, stream>>>(
        w_out, (short*)woutT, 512, 512);
    gather_cast<<<16384, 256, 0, stream>>>(x, agather);
    qkv_gemm<<<dim3(12, 512), 256, 0, stream>>>((const bf16*)agather, wqkvT, b_qkv, qkvbuf);
    attn_kernel<<<dim3(1024, 16), 256, 0, stream>>>(qkvbuf, rel_pos);
    out_gemm<<<dim3(4, 512), 256, 0, stream>>>(qkvbuf, woutT, b_out, out);
}

// Round 3
// 505.602 us; speedup vs baseline: 1.0029x; 1.0029x over previous
//
#include <hip/hip_runtime.h>
#include <hip/hip_bf16.h>
#include <stdint.h>

typedef __hip_bfloat16 bf16;
typedef __attribute__((ext_vector_type(8))) short short8;
typedef __attribute__((ext_vector_type(4))) float f32x4;

#define NWIN 1024
#define NH 16
#define HD 32
#define SHIFT 4

// async global->LDS, 16B per lane; LDS dest is wave-uniform base + lane*16
#define GLOAD_LDS16(gptr, lptr)                                                      \
    __builtin_amdgcn_global_load_lds(                                                \
        (const __attribute__((address_space(1))) void*)(gptr),                       \
        (__attribute__((address_space(3))) void*)(lptr), 16, 0, 0)

// window row r (= win*64 + token) -> source/dest pixel index in (B,64,64) grid.
// Same formula for gather (roll -4) and scatter (roll +4): they are inverses.
__device__ __forceinline__ int row_to_pixel(int r) {
    int win = r >> 6, t = r & 63;
    int b = win >> 6, wy = (win >> 3) & 7, wx = win & 7;
    int h = ((wy << 3) + (t >> 3) + SHIFT) & 63;
    int w = ((wx << 3) + (t & 7) + SHIFT) & 63;
    return (((b << 6) | h) << 6) | w;
}

__device__ __forceinline__ short f2bf_bits(float f) {
    bf16 h = __float2bfloat16(f);
    return *reinterpret_cast<short*>(&h);
}

// fp32 -> bf16 transpose for weights
__global__ void transpose_f2b(const float* __restrict__ src, short* __restrict__ dst,
                              int K, int N) {
    int idx = blockIdx.x * 256 + threadIdx.x;
    if (idx >= K * N) return;
    int k = idx / N, n = idx - k * N;
    dst[n * K + k] = f2bf_bits(src[idx]);
}

// ---------------- pre-pass: gather (cyclic roll + window partition) + fp32->bf16 cast ----------------
// A'[r][k] = bf16(x[row_to_pixel(r)*512 + k]); each thread does 8 contiguous elems.
__global__ __launch_bounds__(256)
void gather_cast(const float* __restrict__ x, short* __restrict__ a) {
    int chunk = blockIdx.x * 256 + threadIdx.x;   // 65536*64 chunks of 8
    int r = chunk >> 6, c8 = (chunk & 63) << 3;
    int pix = row_to_pixel(r);
    const float* src = x + pix * 512 + c8;
    float4 f0 = *(const float4*)src;
    float4 f1 = *(const float4*)(src + 4);
    short8 v;
    v[0] = f2bf_bits(f0.x); v[1] = f2bf_bits(f0.y);
    v[2] = f2bf_bits(f0.z); v[3] = f2bf_bits(f0.w);
    v[4] = f2bf_bits(f1.x); v[5] = f2bf_bits(f1.y);
    v[6] = f2bf_bits(f1.z); v[7] = f2bf_bits(f1.w);
    *(short8*)(a + r * 512 + c8) = v;
}

// ---------------- QKV GEMM: A = pre-gathered bf16 (65536 x 512), B = wqkvT bf16 (1536 x 512) ----------------
// grid = dim3(12, 512): blockIdx.x = n-slab (fastest) for A-panel L2 reuse.
// Staging via global_load_lds width=16 into packed [128][32] LDS (m97 structure).
__global__ __launch_bounds__(256, 2)
void qkv_gemm(const bf16* __restrict__ a, const bf16* __restrict__ wT,
              const float* __restrict__ bqkv, bf16* __restrict__ qkv) {
    __shared__ __align__(16) short As[128 * 32];
    __shared__ __align__(16) short Bs[128 * 32];
    const int tid = threadIdx.x;
    const int lane = tid & 63, wave = tid >> 6;
    const int wr = wave >> 1, wc = wave & 1;
    const int m0 = blockIdx.y * 128, n0 = blockIdx.x * 128;

    // chunk c (0..7) = rows [16c,16c+16) x 32 shorts = 1024B; lane l -> row 16c+(l>>2), col (l&3)*8
    const int lrow = lane >> 2, lc8 = (lane & 3) << 3;
    const short* agA0 = (const short*)a + (m0 + wave * 16 + lrow) * 512 + lc8;
    const short* agA1 = (const short*)a + (m0 + (wave + 4) * 16 + lrow) * 512 + lc8;
    const short* bgB0 = (const short*)wT + (n0 + wave * 16 + lrow) * 512 + lc8;
    const short* bgB1 = (const short*)wT + (n0 + (wave + 4) * 16 + lrow) * 512 + lc8;
    short* ldsA0 = As + wave * 512;
    short* ldsA1 = As + (wave + 4) * 512;
    short* ldsB0 = Bs + wave * 512;
    short* ldsB1 = Bs + (wave + 4) * 512;

    f32x4 acc[4][4] = {};
    for (int k0 = 0; k0 < 512; k0 += 32) {
        __syncthreads();
        GLOAD_LDS16(agA0 + k0, ldsA0);
        GLOAD_LDS16(agA1 + k0, ldsA1);
        GLOAD_LDS16(bgB0 + k0, ldsB0);
        GLOAD_LDS16(bgB1 + k0, ldsB1);
        __syncthreads();
        const int kk = (lane >> 4) << 3;
        short8 af[4], bfr[4];
#pragma unroll
        for (int mt = 0; mt < 4; ++mt)
            af[mt] = *(const short8*)&As[(wr * 64 + mt * 16 + (lane & 15)) * 32 + kk];
#pragma unroll
        for (int nt = 0; nt < 4; ++nt)
            bfr[nt] = *(const short8*)&Bs[(wc * 64 + nt * 16 + (lane & 15)) * 32 + kk];
#pragma unroll
        for (int mt = 0; mt < 4; ++mt)
#pragma unroll
            for (int nt = 0; nt < 4; ++nt)
                acc[mt][nt] = __builtin_amdgcn_mfma_f32_16x16x32_bf16(af[mt], bfr[nt],
                                                                      acc[mt][nt], 0, 0, 0);
    }

    // epilogue: C/D layout col=lane&15, row=(lane>>4)*4+reg [m89]
#pragma unroll
    for (int mt = 0; mt < 4; ++mt) {
        int rbase = m0 + wr * 64 + mt * 16 + ((lane >> 4) << 2);
#pragma unroll
        for (int nt = 0; nt < 4; ++nt) {
            int c = n0 + wc * 64 + nt * 16 + (lane & 15);
            int which = c >> 9, head = (c >> 5) & 15, d = c & 31;
            float bias = bqkv[c];
            float scale = (which == 0) ? 0.17677669529663689f : 1.0f;
#pragma unroll
            for (int reg = 0; reg < 4; ++reg) {
                int r = rbase + reg;
                int win = r >> 6, t = r & 63;
                float v = (acc[mt][nt][reg] + bias) * scale;
                qkv[(((which * NWIN + win) * NH + head) * 64 + t) * HD + d] = __float2bfloat16(v);
            }
        }
    }
}

// ---------------- attention: one block per (window, head) ----------------
__global__ __launch_bounds__(256, 2)
void attn_kernel(bf16* __restrict__ qkv, const float* __restrict__ relpos) {
    const int win = blockIdx.x, head = blockIdx.y;
    __shared__ __align__(16) short qs[64 * 40];
    __shared__ __align__(16) short ks[64 * 40];
    __shared__ __align__(16) short vT[32 * 72];
    __shared__ float Ss[64 * 65];
    __shared__ __align__(16) short Ps[64 * 72];
    __shared__ float rel[225];
    const int tid = threadIdx.x, lane = tid & 63, wave = tid >> 6;
    const int base = (win * NH + head) * 2048;
    const short* qg = (const short*)qkv + base;
    const short* kg = qg + NWIN * NH * 2048;
    const short* vg = kg + NWIN * NH * 2048;

    {
        int row = tid >> 2, c8 = (tid & 3) << 3;
        *(short8*)&qs[row * 40 + c8] = *(const short8*)(qg + row * 32 + c8);
        *(short8*)&ks[row * 40 + c8] = *(const short8*)(kg + row * 32 + c8);
        short8 vv = *(const short8*)(vg + row * 32 + c8);
#pragma unroll
        for (int e = 0; e < 8; ++e) vT[(c8 + e) * 72 + row] = vv[e];
    }
    if (tid < 225) rel[tid] = relpos[tid * 16 + head];   // only this head's column
    __syncthreads();

    // S = q k^T (q pre-scaled); wave handles 16 q-rows x 64 keys
    {
        const int kk = (lane >> 4) << 3;
        short8 aq = *(const short8*)&qs[(wave * 16 + (lane & 15)) * 40 + kk];
        f32x4 sacc[4];
#pragma unroll
        for (int nt = 0; nt < 4; ++nt) {
            short8 bk = *(const short8*)&ks[(nt * 16 + (lane & 15)) * 40 + kk];
            f32x4 z = {};
            sacc[nt] = __builtin_amdgcn_mfma_f32_16x16x32_bf16(aq, bk, z, 0, 0, 0);
        }
#pragma unroll
        for (int nt = 0; nt < 4; ++nt)
#pragma unroll
            for (int reg = 0; reg < 4; ++reg) {
                int qt = wave * 16 + ((lane >> 4) << 2) + reg;
                int kt = nt * 16 + (lane & 15);
                int idx = ((qt >> 3) - (kt >> 3) + 7) * 15 + ((qt & 7) - (kt & 7) + 7);
                Ss[qt * 65 + kt] = sacc[nt][reg] + rel[idx];
            }
    }
    __syncthreads();

    // fp32 softmax: 4 lanes per row, quad shuffle reduce
    {
        int row = tid >> 2, col0 = (tid & 3) << 4;
        float v[16];
        float m = -3e38f;
#pragma unroll
        for (int e = 0; e < 16; ++e) { v[e] = Ss[row * 65 + col0 + e]; m = fmaxf(m, v[e]); }
        m = fmaxf(m, __shfl_xor(m, 1));
        m = fmaxf(m, __shfl_xor(m, 2));
        float s = 0.f;
#pragma unroll
        for (int e = 0; e < 16; ++e) { v[e] = __expf(v[e] - m); s += v[e]; }
        s += __shfl_xor(s, 1);
        s += __shfl_xor(s, 2);
        float inv = 1.f / s;
#pragma unroll
        for (int e = 0; e < 16; ++e) Ps[row * 72 + col0 + e] = f2bf_bits(v[e] * inv);
    }
    __syncthreads();

    // O = P V : wave -> 16 rows x 32 dims, K=64 in 2 steps
    {
        f32x4 oacc[2] = {};
#pragma unroll
        for (int kstep = 0; kstep < 2; ++kstep) {
            const int kk = kstep * 32 + ((lane >> 4) << 3);
            short8 ap = *(const short8*)&Ps[(wave * 16 + (lane & 15)) * 72 + kk];
#pragma unroll
            for (int nt = 0; nt < 2; ++nt) {
                short8 bv = *(const short8*)&vT[(nt * 16 + (lane & 15)) * 72 + kk];
                oacc[nt] = __builtin_amdgcn_mfma_f32_16x16x32_bf16(ap, bv, oacc[nt], 0, 0, 0);
            }
        }
        short* og = (short*)qkv + base;  // overwrite q slice (disjoint per block)
#pragma unroll
        for (int nt = 0; nt < 2; ++nt)
#pragma unroll
            for (int reg = 0; reg < 4; ++reg) {
                int t = wave * 16 + ((lane >> 4) << 2) + reg;
                int d = nt * 16 + (lane & 15);
                og[t * 32 + d] = f2bf_bits(oacc[nt][reg]);
            }
    }
}

// ---------------- out projection GEMM: A = attn out (q slice), scatter fp32 with roll ----------------
// grid = dim3(4, 512); global_load_lds staging like qkv_gemm.
__global__ __launch_bounds__(256, 2)
void out_gemm(const bf16* __restrict__ ain, const bf16* __restrict__ wT,
              const float* __restrict__ bout, float* __restrict__ out) {
    __shared__ __align__(16) short As[128 * 32];
    __shared__ __align__(16) short Bs[128 * 32];
    const int tid = threadIdx.x;
    const int lane = tid & 63, wave = tid >> 6;
    const int wr = wave >> 1, wc = wave & 1;
    const int m0 = blockIdx.y * 128, n0 = blockIdx.x * 128;

    const int lrow = lane >> 2, lc8 = (lane & 3) << 3;
    // A[r][k]: k = head*32+d -> ain[((win*16+head)*64 + t)*32 + d]; +k0 step = k0*64 elems
    const short* agA[2];
    const short* bgB[2];
    short* ldsA[2];
    short* ldsB[2];
#pragma unroll
    for (int s = 0; s < 2; ++s) {
        int c = wave + s * 4;
        int r = m0 + c * 16 + lrow, win = r >> 6, t = r & 63;
        agA[s] = (const short*)ain + win * 32768 + t * 32 + lc8;
        bgB[s] = (const short*)wT + (n0 + c * 16 + lrow) * 512 + lc8;
        ldsA[s] = As + c * 512;
        ldsB[s] = Bs + c * 512;
    }

    f32x4 acc[4][4] = {};
    for (int k0 = 0; k0 < 512; k0 += 32) {
        __syncthreads();
        GLOAD_LDS16(agA[0] + k0 * 64, ldsA[0]);
        GLOAD_LDS16(agA[1] + k0 * 64, ldsA[1]);
        GLOAD_LDS16(bgB[0] + k0, ldsB[0]);
        GLOAD_LDS16(bgB[1] + k0, ldsB[1]);
        __syncthreads();
        const int kk = (lane >> 4) << 3;
        short8 af[4], bfr[4];
#pragma unroll
        for (int mt = 0; mt < 4; ++mt)
            af[mt] = *(const short8*)&As[(wr * 64 + mt * 16 + (lane & 15)) * 32 + kk];
#pragma unroll
        for (int nt = 0; nt < 4; ++nt)
            bfr[nt] = *(const short8*)&Bs[(wc * 64 + nt * 16 + (lane & 15)) * 32 + kk];
#pragma unroll
        for (int mt = 0; mt < 4; ++mt)
#pragma unroll
            for (int nt = 0; nt < 4; ++nt)
                acc[mt][nt] = __builtin_amdgcn_mfma_f32_16x16x32_bf16(af[mt], bfr[nt],
                                                                      acc[mt][nt], 0, 0, 0);
    }

#pragma unroll
    for (int mt = 0; mt < 4; ++mt) {
        int rbase = m0 + wr * 64 + mt * 16 + ((lane >> 4) << 2);
#pragma unroll
        for (int nt = 0; nt < 4; ++nt) {
            int c = n0 + wc * 64 + nt * 16 + (lane & 15);
            float bias = bout[c];
#pragma unroll
            for (int reg = 0; reg < 4; ++reg) {
                int r = rbase + reg;
                int pix = row_to_pixel(r);
                out[pix * 512 + c] = acc[mt][nt][reg] + bias;
            }
        }
    }
}

extern "C" void kernel_launch(void* const* d_in, const int* in_sizes, int n_in,
                              void* d_out, int out_size, void* d_ws, size_t ws_size,
                              hipStream_t stream) {
    const float* x       = (const float*)d_in[0];   // (16,64,64,512) fp32
    const float* w_qkv   = (const float*)d_in[1];   // (512,1536) fp32
    const float* b_qkv   = (const float*)d_in[2];   // (1536,) fp32
    const float* rel_pos = (const float*)d_in[3];   // (225,16) fp32
    const float* w_out   = (const float*)d_in[4];   // (512,512) fp32
    const float* b_out   = (const float*)d_in[5];   // (512,) fp32
    float* out = (float*)d_out;

    bf16* wqkvT  = (bf16*)d_ws;                  // 1536*512 bf16
    bf16* woutT  = wqkvT + 1536 * 512;           // 512*512 bf16
    bf16* qkvbuf = woutT + 512 * 512;            // 3*1024*16*64*32 bf16 (~201 MB)

    // A' (gathered bf16 x, 65536x512 = 67 MB) lives in d_out: it is fully
    // consumed by qkv_gemm before out_gemm overwrites d_out at the end.
    short* agather = (short*)d_out;

    transpose_f2b<<<(512 * 1536 + 255) / 256, 256, 0, stream>>>(
        w_qkv, (short*)wqkvT, 512, 1536);
    transpose_f2b<<<(512 * 512 + 255) / 256, 256, 0, stream>>>(
        w_out, (short*)woutT, 512, 512);
    gather_cast<<<16384, 256, 0, stream>>>(x, agather);
    qkv_gemm<<<dim3(12, 512), 256, 0, stream>>>((const bf16*)agather, wqkvT, b_qkv, qkvbuf);
    attn_kernel<<<dim3(1024, 16), 256, 0, stream>>>(qkvbuf, rel_pos);
    out_gemm<<<dim3(4, 512), 256, 0, stream>>>(qkvbuf, woutT, b_out, out);
}

// Round 4
// 490.898 us; speedup vs baseline: 1.0329x; 1.0300x over previous
//
#include <hip/hip_runtime.h>
#include <hip/hip_bf16.h>
#include <stdint.h>

typedef __hip_bfloat16 bf16;
typedef __attribute__((ext_vector_type(8))) short short8;
typedef __attribute__((ext_vector_type(4))) float f32x4;

#define NWIN 1024
#define NH 16
#define HD 32
#define SHIFT 4

// async global->LDS, 16B per lane; LDS dest is wave-uniform base + lane*16
#define GLOAD_LDS16(gptr, lptr)                                                      \
    __builtin_amdgcn_global_load_lds(                                                \
        (const __attribute__((address_space(1))) void*)(gptr),                       \
        (__attribute__((address_space(3))) void*)(lptr), 16, 0, 0)

// window row r (= win*64 + token) -> source/dest pixel index in (B,64,64) grid.
// Same formula for gather (roll -4) and scatter (roll +4): they are inverses.
__device__ __forceinline__ int row_to_pixel(int r) {
    int win = r >> 6, t = r & 63;
    int b = win >> 6, wy = (win >> 3) & 7, wx = win & 7;
    int h = ((wy << 3) + (t >> 3) + SHIFT) & 63;
    int w = ((wx << 3) + (t & 7) + SHIFT) & 63;
    return (((b << 6) | h) << 6) | w;
}

__device__ __forceinline__ short f2bf_bits(float f) {
    bf16 h = __float2bfloat16(f);
    return *reinterpret_cast<short*>(&h);
}

// fp32 -> bf16 transpose for weights
__global__ void transpose_f2b(const float* __restrict__ src, short* __restrict__ dst,
                              int K, int N) {
    int idx = blockIdx.x * 256 + threadIdx.x;
    if (idx >= K * N) return;
    int k = idx / N, n = idx - k * N;
    dst[n * K + k] = f2bf_bits(src[idx]);
}

// ---------------- pre-pass: gather (cyclic roll + window partition) + fp32->bf16 cast ----------------
__global__ __launch_bounds__(256)
void gather_cast(const float* __restrict__ x, short* __restrict__ a) {
    int chunk = blockIdx.x * 256 + threadIdx.x;   // 65536*64 chunks of 8
    int r = chunk >> 6, c8 = (chunk & 63) << 3;
    int pix = row_to_pixel(r);
    const float* src = x + pix * 512 + c8;
    float4 f0 = *(const float4*)src;
    float4 f1 = *(const float4*)(src + 4);
    short8 v;
    v[0] = f2bf_bits(f0.x); v[1] = f2bf_bits(f0.y);
    v[2] = f2bf_bits(f0.z); v[3] = f2bf_bits(f0.w);
    v[4] = f2bf_bits(f1.x); v[5] = f2bf_bits(f1.y);
    v[6] = f2bf_bits(f1.z); v[7] = f2bf_bits(f1.w);
    *(short8*)(a + r * 512 + c8) = v;
}

// ---------------- QKV GEMM: A = pre-gathered bf16 (65536 x 512), B = wqkvT bf16 (1536 x 512) ----------------
// 1D grid 6144 with chunked XCD swizzle: each XCD gets 64 consecutive m-panels
// (all 12 n-blocks of a panel on ONE XCD -> A-panel fetched once into that L2).
__global__ __launch_bounds__(256, 4)
void qkv_gemm(const bf16* __restrict__ a, const bf16* __restrict__ wT,
              const float* __restrict__ bqkv, bf16* __restrict__ qkv) {
    __shared__ __align__(16) short As[128 * 32];
    __shared__ __align__(16) short Bs[128 * 32];
    const int tid = threadIdx.x;
    const int lane = tid & 63, wave = tid >> 6;
    const int wr = wave >> 1, wc = wave & 1;
    const int h = blockIdx.x;
    const int v = (h & 7) * 768 + (h >> 3);   // bijective: 6144 % 8 == 0
    const int by = v / 12, bx = v - by * 12;
    const int m0 = by * 128, n0 = bx * 128;

    // chunk c (0..7) = rows [16c,16c+16) x 32 shorts = 1024B; lane l -> row 16c+(l>>2), col (l&3)*8
    const int lrow = lane >> 2, lc8 = (lane & 3) << 3;
    const short* agA0 = (const short*)a + (m0 + wave * 16 + lrow) * 512 + lc8;
    const short* agA1 = (const short*)a + (m0 + (wave + 4) * 16 + lrow) * 512 + lc8;
    const short* bgB0 = (const short*)wT + (n0 + wave * 16 + lrow) * 512 + lc8;
    const short* bgB1 = (const short*)wT + (n0 + (wave + 4) * 16 + lrow) * 512 + lc8;
    short* ldsA0 = As + wave * 512;
    short* ldsA1 = As + (wave + 4) * 512;
    short* ldsB0 = Bs + wave * 512;
    short* ldsB1 = Bs + (wave + 4) * 512;

    f32x4 acc[4][4] = {};
    for (int k0 = 0; k0 < 512; k0 += 32) {
        __syncthreads();
        GLOAD_LDS16(agA0 + k0, ldsA0);
        GLOAD_LDS16(agA1 + k0, ldsA1);
        GLOAD_LDS16(bgB0 + k0, ldsB0);
        GLOAD_LDS16(bgB1 + k0, ldsB1);
        __syncthreads();
        const int kk = (lane >> 4) << 3;
        short8 af[4], bfr[4];
#pragma unroll
        for (int mt = 0; mt < 4; ++mt)
            af[mt] = *(const short8*)&As[(wr * 64 + mt * 16 + (lane & 15)) * 32 + kk];
#pragma unroll
        for (int nt = 0; nt < 4; ++nt)
            bfr[nt] = *(const short8*)&Bs[(wc * 64 + nt * 16 + (lane & 15)) * 32 + kk];
#pragma unroll
        for (int mt = 0; mt < 4; ++mt)
#pragma unroll
            for (int nt = 0; nt < 4; ++nt)
                acc[mt][nt] = __builtin_amdgcn_mfma_f32_16x16x32_bf16(af[mt], bfr[nt],
                                                                      acc[mt][nt], 0, 0, 0);
    }

    // epilogue: C/D layout col=lane&15, row=(lane>>4)*4+reg [m89]
    // r0..r0+3 stay in one win (r0 % 4 == 0), so hoist base addr; stores use imm offsets.
#pragma unroll
    for (int mt = 0; mt < 4; ++mt) {
        int r0 = m0 + wr * 64 + mt * 16 + ((lane >> 4) << 2);
        int win = r0 >> 6, t0 = r0 & 63;
#pragma unroll
        for (int nt = 0; nt < 4; ++nt) {
            int c = n0 + wc * 64 + nt * 16 + (lane & 15);
            int which = c >> 9, head = (c >> 5) & 15, d = c & 31;
            float bias = bqkv[c];
            float scale = (which == 0) ? 0.17677669529663689f : 1.0f;
            short* p = (short*)qkv + (((which * NWIN + win) * NH + head) * 64 + t0) * HD + d;
#pragma unroll
            for (int reg = 0; reg < 4; ++reg)
                p[reg * HD] = f2bf_bits((acc[mt][nt][reg] + bias) * scale);
        }
    }
}

// ---------------- attention: one block per (window, head) ----------------
__global__ __launch_bounds__(256, 2)
void attn_kernel(bf16* __restrict__ qkv, const float* __restrict__ relpos) {
    const int win = blockIdx.x, head = blockIdx.y;
    __shared__ __align__(16) short qs[64 * 40];
    __shared__ __align__(16) short ks[64 * 40];
    __shared__ __align__(16) short vT[32 * 72];
    __shared__ float Ss[64 * 65];
    __shared__ __align__(16) short Ps[64 * 72];
    __shared__ float rel[225];
    const int tid = threadIdx.x, lane = tid & 63, wave = tid >> 6;
    const int base = (win * NH + head) * 2048;
    const short* qg = (const short*)qkv + base;
    const short* kg = qg + NWIN * NH * 2048;
    const short* vg = kg + NWIN * NH * 2048;

    {
        int row = tid >> 2, c8 = (tid & 3) << 3;
        *(short8*)&qs[row * 40 + c8] = *(const short8*)(qg + row * 32 + c8);
        *(short8*)&ks[row * 40 + c8] = *(const short8*)(kg + row * 32 + c8);
        short8 vv = *(const short8*)(vg + row * 32 + c8);
#pragma unroll
        for (int e = 0; e < 8; ++e) vT[(c8 + e) * 72 + row] = vv[e];
    }
    if (tid < 225) rel[tid] = relpos[tid * 16 + head];   // only this head's column
    __syncthreads();

    // S = q k^T (q pre-scaled); wave handles 16 q-rows x 64 keys
    {
        const int kk = (lane >> 4) << 3;
        short8 aq = *(const short8*)&qs[(wave * 16 + (lane & 15)) * 40 + kk];
        f32x4 sacc[4];
#pragma unroll
        for (int nt = 0; nt < 4; ++nt) {
            short8 bk = *(const short8*)&ks[(nt * 16 + (lane & 15)) * 40 + kk];
            f32x4 z = {};
            sacc[nt] = __builtin_amdgcn_mfma_f32_16x16x32_bf16(aq, bk, z, 0, 0, 0);
        }
#pragma unroll
        for (int nt = 0; nt < 4; ++nt)
#pragma unroll
            for (int reg = 0; reg < 4; ++reg) {
                int qt = wave * 16 + ((lane >> 4) << 2) + reg;
                int kt = nt * 16 + (lane & 15);
                int idx = ((qt >> 3) - (kt >> 3) + 7) * 15 + ((qt & 7) - (kt & 7) + 7);
                Ss[qt * 65 + kt] = sacc[nt][reg] + rel[idx];
            }
    }
    __syncthreads();

    // fp32 softmax: 4 lanes per row, quad shuffle reduce
    {
        int row = tid >> 2, col0 = (tid & 3) << 4;
        float v[16];
        float m = -3e38f;
#pragma unroll
        for (int e = 0; e < 16; ++e) { v[e] = Ss[row * 65 + col0 + e]; m = fmaxf(m, v[e]); }
        m = fmaxf(m, __shfl_xor(m, 1));
        m = fmaxf(m, __shfl_xor(m, 2));
        float s = 0.f;
#pragma unroll
        for (int e = 0; e < 16; ++e) { v[e] = __expf(v[e] - m); s += v[e]; }
        s += __shfl_xor(s, 1);
        s += __shfl_xor(s, 2);
        float inv = 1.f / s;
#pragma unroll
        for (int e = 0; e < 16; ++e) Ps[row * 72 + col0 + e] = f2bf_bits(v[e] * inv);
    }
    __syncthreads();

    // O = P V : wave -> 16 rows x 32 dims, K=64 in 2 steps
    {
        f32x4 oacc[2] = {};
#pragma unroll
        for (int kstep = 0; kstep < 2; ++kstep) {
            const int kk = kstep * 32 + ((lane >> 4) << 3);
            short8 ap = *(const short8*)&Ps[(wave * 16 + (lane & 15)) * 72 + kk];
#pragma unroll
            for (int nt = 0; nt < 2; ++nt) {
                short8 bv = *(const short8*)&vT[(nt * 16 + (lane & 15)) * 72 + kk];
                oacc[nt] = __builtin_amdgcn_mfma_f32_16x16x32_bf16(ap, bv, oacc[nt], 0, 0, 0);
            }
        }
        short* og = (short*)qkv + base;  // overwrite q slice (disjoint per block)
#pragma unroll
        for (int nt = 0; nt < 2; ++nt)
#pragma unroll
            for (int reg = 0; reg < 4; ++reg) {
                int t = wave * 16 + ((lane >> 4) << 2) + reg;
                int d = nt * 16 + (lane & 15);
                og[t * 32 + d] = f2bf_bits(oacc[nt][reg]);
            }
    }
}

// ---------------- out projection GEMM: A = attn out (q slice), scatter fp32 with roll ----------------
// 1D grid 2048 with chunked XCD swizzle (same rationale as qkv_gemm).
__global__ __launch_bounds__(256, 4)
void out_gemm(const bf16* __restrict__ ain, const bf16* __restrict__ wT,
              const float* __restrict__ bout, float* __restrict__ out) {
    __shared__ __align__(16) short As[128 * 32];
    __shared__ __align__(16) short Bs[128 * 32];
    const int tid = threadIdx.x;
    const int lane = tid & 63, wave = tid >> 6;
    const int wr = wave >> 1, wc = wave & 1;
    const int h = blockIdx.x;
    const int v = (h & 7) * 256 + (h >> 3);   // bijective: 2048 % 8 == 0
    const int bx = v & 3, by = v >> 2;
    const int m0 = by * 128, n0 = bx * 128;

    const int lrow = lane >> 2, lc8 = (lane & 3) << 3;
    // A[r][k]: k = head*32+d -> ain[((win*16+head)*64 + t)*32 + d]; +k0 step = k0*64 elems
    const short* agA[2];
    const short* bgB[2];
    short* ldsA[2];
    short* ldsB[2];
#pragma unroll
    for (int s = 0; s < 2; ++s) {
        int c = wave + s * 4;
        int r = m0 + c * 16 + lrow, win = r >> 6, t = r & 63;
        agA[s] = (const short*)ain + win * 32768 + t * 32 + lc8;
        bgB[s] = (const short*)wT + (n0 + c * 16 + lrow) * 512 + lc8;
        ldsA[s] = As + c * 512;
        ldsB[s] = Bs + c * 512;
    }

    f32x4 acc[4][4] = {};
    for (int k0 = 0; k0 < 512; k0 += 32) {
        __syncthreads();
        GLOAD_LDS16(agA[0] + k0 * 64, ldsA[0]);
        GLOAD_LDS16(agA[1] + k0 * 64, ldsA[1]);
        GLOAD_LDS16(bgB[0] + k0, ldsB[0]);
        GLOAD_LDS16(bgB[1] + k0, ldsB[1]);
        __syncthreads();
        const int kk = (lane >> 4) << 3;
        short8 af[4], bfr[4];
#pragma unroll
        for (int mt = 0; mt < 4; ++mt)
            af[mt] = *(const short8*)&As[(wr * 64 + mt * 16 + (lane & 15)) * 32 + kk];
#pragma unroll
        for (int nt = 0; nt < 4; ++nt)
            bfr[nt] = *(const short8*)&Bs[(wc * 64 + nt * 16 + (lane & 15)) * 32 + kk];
#pragma unroll
        for (int mt = 0; mt < 4; ++mt)
#pragma unroll
            for (int nt = 0; nt < 4; ++nt)
                acc[mt][nt] = __builtin_amdgcn_mfma_f32_16x16x32_bf16(af[mt], bfr[nt],
                                                                      acc[mt][nt], 0, 0, 0);
    }

    // epilogue: pix(r0+reg) == pix(r0)+reg within the 4-row group (w stays multiple of 4 after wrap)
#pragma unroll
    for (int mt = 0; mt < 4; ++mt) {
        int r0 = m0 + wr * 64 + mt * 16 + ((lane >> 4) << 2);
        int pix0 = row_to_pixel(r0);
#pragma unroll
        for (int nt = 0; nt < 4; ++nt) {
            int c = n0 + wc * 64 + nt * 16 + (lane & 15);
            float bias = bout[c];
            float* po = out + pix0 * 512 + c;
#pragma unroll
            for (int reg = 0; reg < 4; ++reg)
                po[reg * 512] = acc[mt][nt][reg] + bias;
        }
    }
}

extern "C" void kernel_launch(void* const* d_in, const int* in_sizes, int n_in,
                              void* d_out, int out_size, void* d_ws, size_t ws_size,
                              hipStream_t stream) {
    const float* x       = (const float*)d_in[0];   // (16,64,64,512) fp32
    const float* w_qkv   = (const float*)d_in[1];   // (512,1536) fp32
    const float* b_qkv   = (const float*)d_in[2];   // (1536,) fp32
    const float* rel_pos = (const float*)d_in[3];   // (225,16) fp32
    const float* w_out   = (const float*)d_in[4];   // (512,512) fp32
    const float* b_out   = (const float*)d_in[5];   // (512,) fp32
    float* out = (float*)d_out;

    bf16* wqkvT  = (bf16*)d_ws;                  // 1536*512 bf16
    bf16* woutT  = wqkvT + 1536 * 512;           // 512*512 bf16
    bf16* qkvbuf = woutT + 512 * 512;            // 3*1024*16*64*32 bf16 (~201 MB)

    // A' (gathered bf16 x, 65536x512 = 67 MB) lives in d_out: it is fully
    // consumed by qkv_gemm before out_gemm overwrites d_out at the end.
    short* agather = (short*)d_out;

    transpose_f2b<<<(512 * 1536 + 255) / 256, 256, 0, stream>>>(
        w_qkv, (short*)wqkvT, 512, 1536);
    transpose_f2b<<<(512 * 512 + 255) / 256, 256, 0, stream>>>(
        w_out, (short*)woutT, 512, 512);
    gather_cast<<<16384, 256, 0, stream>>>(x, agather);
    qkv_gemm<<<6144, 256, 0, stream>>>((const bf16*)agather, wqkvT, b_qkv, qkvbuf);
    attn_kernel<<<dim3(1024, 16), 256, 0, stream>>>(qkvbuf, rel_pos);
    out_gemm<<<2048, 256, 0, stream>>>(qkvbuf, woutT, b_out, out);
}

// Round 6
// 485.748 us; speedup vs baseline: 1.0439x; 1.0106x over previous
//
#include <hip/hip_runtime.h>
#include <hip/hip_bf16.h>
#include <stdint.h>

typedef __hip_bfloat16 bf16;
typedef __attribute__((ext_vector_type(8))) short short8;
typedef __attribute__((ext_vector_type(4))) float f32x4;

#define NWIN 1024
#define NH 16
#define HD 32
#define SHIFT 4

// async global->LDS, 16B per lane; LDS dest is wave-uniform base + lane*16
#define GLOAD_LDS16(gptr, lptr)                                                      \
    __builtin_amdgcn_global_load_lds(                                                \
        (const __attribute__((address_space(1))) void*)(gptr),                       \
        (__attribute__((address_space(3))) void*)(lptr), 16, 0, 0)

// window row r (= win*64 + token) -> source/dest pixel index in (B,64,64) grid.
// Same formula for gather (roll -4) and scatter (roll +4): they are inverses.
__device__ __forceinline__ int row_to_pixel(int r) {
    int win = r >> 6, t = r & 63;
    int b = win >> 6, wy = (win >> 3) & 7, wx = win & 7;
    int h = ((wy << 3) + (t >> 3) + SHIFT) & 63;
    int w = ((wx << 3) + (t & 7) + SHIFT) & 63;
    return (((b << 6) | h) << 6) | w;
}

__device__ __forceinline__ short f2bf_bits(float f) {
    bf16 h = __float2bfloat16(f);
    return *reinterpret_cast<short*>(&h);
}

// fp32 -> bf16 transpose for weights
__global__ void transpose_f2b(const float* __restrict__ src, short* __restrict__ dst,
                              int K, int N) {
    int idx = blockIdx.x * 256 + threadIdx.x;
    if (idx >= K * N) return;
    int k = idx / N, n = idx - k * N;
    dst[n * K + k] = f2bf_bits(src[idx]);
}

// ---------------- pre-pass: gather (cyclic roll + window partition) + fp32->bf16 cast ----------------
__global__ __launch_bounds__(256)
void gather_cast(const float* __restrict__ x, short* __restrict__ a) {
    int chunk = blockIdx.x * 256 + threadIdx.x;   // 65536*64 chunks of 8
    int r = chunk >> 6, c8 = (chunk & 63) << 3;
    int pix = row_to_pixel(r);
    const float* src = x + pix * 512 + c8;
    float4 f0 = *(const float4*)src;
    float4 f1 = *(const float4*)(src + 4);
    short8 v;
    v[0] = f2bf_bits(f0.x); v[1] = f2bf_bits(f0.y);
    v[2] = f2bf_bits(f0.z); v[3] = f2bf_bits(f0.w);
    v[4] = f2bf_bits(f1.x); v[5] = f2bf_bits(f1.y);
    v[6] = f2bf_bits(f1.z); v[7] = f2bf_bits(f1.w);
    *(short8*)(a + r * 512 + c8) = v;
}

// ---------------- QKV GEMM: A = pre-gathered bf16 (65536 x 512), B = wqkvT bf16 (1536 x 512) ----------------
// 1D grid 6144 with chunked XCD swizzle: each XCD gets 64 consecutive m-panels
// (all 12 n-blocks of a panel on ONE XCD -> A-panel fetched once into that L2).
__global__ __launch_bounds__(256, 4)
void qkv_gemm(const bf16* __restrict__ a, const bf16* __restrict__ wT,
              const float* __restrict__ bqkv, bf16* __restrict__ qkv) {
    __shared__ __align__(16) short As[128 * 32];
    __shared__ __align__(16) short Bs[128 * 32];
    const int tid = threadIdx.x;
    const int lane = tid & 63, wave = tid >> 6;
    const int wr = wave >> 1, wc = wave & 1;
    const int h = blockIdx.x;
    const int v = (h & 7) * 768 + (h >> 3);   // bijective: 6144 % 8 == 0
    const int by = v / 12, bx = v - by * 12;
    const int m0 = by * 128, n0 = bx * 128;

    // chunk c (0..7) = rows [16c,16c+16) x 32 shorts = 1024B; lane l -> row 16c+(l>>2), col (l&3)*8
    const int lrow = lane >> 2, lc8 = (lane & 3) << 3;
    const short* agA0 = (const short*)a + (m0 + wave * 16 + lrow) * 512 + lc8;
    const short* agA1 = (const short*)a + (m0 + (wave + 4) * 16 + lrow) * 512 + lc8;
    const short* bgB0 = (const short*)wT + (n0 + wave * 16 + lrow) * 512 + lc8;
    const short* bgB1 = (const short*)wT + (n0 + (wave + 4) * 16 + lrow) * 512 + lc8;
    short* ldsA0 = As + wave * 512;
    short* ldsA1 = As + (wave + 4) * 512;
    short* ldsB0 = Bs + wave * 512;
    short* ldsB1 = Bs + (wave + 4) * 512;

    f32x4 acc[4][4] = {};
    for (int k0 = 0; k0 < 512; k0 += 32) {
        __syncthreads();
        GLOAD_LDS16(agA0 + k0, ldsA0);
        GLOAD_LDS16(agA1 + k0, ldsA1);
        GLOAD_LDS16(bgB0 + k0, ldsB0);
        GLOAD_LDS16(bgB1 + k0, ldsB1);
        __syncthreads();
        const int kk = (lane >> 4) << 3;
        short8 af[4], bfr[4];
#pragma unroll
        for (int mt = 0; mt < 4; ++mt)
            af[mt] = *(const short8*)&As[(wr * 64 + mt * 16 + (lane & 15)) * 32 + kk];
#pragma unroll
        for (int nt = 0; nt < 4; ++nt)
            bfr[nt] = *(const short8*)&Bs[(wc * 64 + nt * 16 + (lane & 15)) * 32 + kk];
#pragma unroll
        for (int mt = 0; mt < 4; ++mt)
#pragma unroll
            for (int nt = 0; nt < 4; ++nt)
                acc[mt][nt] = __builtin_amdgcn_mfma_f32_16x16x32_bf16(af[mt], bfr[nt],
                                                                      acc[mt][nt], 0, 0, 0);
    }

    // epilogue: C/D layout col=lane&15, row=(lane>>4)*4+reg [m89]
    // r0..r0+3 stay in one win (r0 % 4 == 0), so hoist base addr; stores use imm offsets.
#pragma unroll
    for (int mt = 0; mt < 4; ++mt) {
        int r0 = m0 + wr * 64 + mt * 16 + ((lane >> 4) << 2);
        int win = r0 >> 6, t0 = r0 & 63;
#pragma unroll
        for (int nt = 0; nt < 4; ++nt) {
            int c = n0 + wc * 64 + nt * 16 + (lane & 15);
            int which = c >> 9, head = (c >> 5) & 15, d = c & 31;
            float bias = bqkv[c];
            float scale = (which == 0) ? 0.17677669529663689f : 1.0f;
            short* p = (short*)qkv + (((which * NWIN + win) * NH + head) * 64 + t0) * HD + d;
#pragma unroll
            for (int reg = 0; reg < 4; ++reg)
                p[reg * HD] = f2bf_bits((acc[mt][nt][reg] + bias) * scale);
        }
    }
}

// ---------------- attention: one block per (window, head) ----------------
// Softmax done in MFMA C-layout (shfl_xor row-reduce) -> no Ss buffer, 1 barrier total,
// 4 blocks/CU (LDS ~24.4 KB).
__global__ __launch_bounds__(256, 4)
void attn_kernel(bf16* __restrict__ qkv, const float* __restrict__ relpos) {
    const int win = blockIdx.x, head = blockIdx.y;
    __shared__ __align__(16) short qs[64 * 40];
    __shared__ __align__(16) short ks[64 * 40];
    __shared__ __align__(16) short vT[32 * 72];
    __shared__ __align__(16) short Ps[64 * 72];
    __shared__ float rel[225];
    const int tid = threadIdx.x, lane = tid & 63, wave = tid >> 6;
    const int base = (win * NH + head) * 2048;
    const short* qg = (const short*)qkv + base;
    const short* kg = qg + NWIN * NH * 2048;
    const short* vg = kg + NWIN * NH * 2048;

    {
        int row = tid >> 2, c8 = (tid & 3) << 3;
        *(short8*)&qs[row * 40 + c8] = *(const short8*)(qg + row * 32 + c8);
        *(short8*)&ks[row * 40 + c8] = *(const short8*)(kg + row * 32 + c8);
        short8 vv = *(const short8*)(vg + row * 32 + c8);
#pragma unroll
        for (int e = 0; e < 8; ++e) vT[(c8 + e) * 72 + row] = vv[e];
    }
    if (tid < 225) rel[tid] = relpos[tid * 16 + head];   // only this head's column
    __syncthreads();

    // S = q k^T (q pre-scaled); wave handles 16 q-rows x 64 keys.
    // Softmax directly in C-layout: row qt fixed per (lane>>4, reg); cols spread over
    // nt (in-lane) and lane&15 (16 lanes sharing lane>>4) -> shfl_xor 1/2/4/8 reduce.
    {
        const int kk = (lane >> 4) << 3;
        short8 aq = *(const short8*)&qs[(wave * 16 + (lane & 15)) * 40 + kk];
        f32x4 sacc[4];
#pragma unroll
        for (int nt = 0; nt < 4; ++nt) {
            short8 bk = *(const short8*)&ks[(nt * 16 + (lane & 15)) * 40 + kk];
            f32x4 z = {};
            sacc[nt] = __builtin_amdgcn_mfma_f32_16x16x32_bf16(aq, bk, z, 0, 0, 0);
        }
#pragma unroll
        for (int reg = 0; reg < 4; ++reg) {
            int qt = wave * 16 + ((lane >> 4) << 2) + reg;
            float pv[4];
            float m = -3e38f;
#pragma unroll
            for (int nt = 0; nt < 4; ++nt) {
                int kt = nt * 16 + (lane & 15);
                int idx = ((qt >> 3) - (kt >> 3) + 7) * 15 + ((qt & 7) - (kt & 7) + 7);
                pv[nt] = sacc[nt][reg] + rel[idx];
                m = fmaxf(m, pv[nt]);
            }
            m = fmaxf(m, __shfl_xor(m, 1));
            m = fmaxf(m, __shfl_xor(m, 2));
            m = fmaxf(m, __shfl_xor(m, 4));
            m = fmaxf(m, __shfl_xor(m, 8));
            float s = 0.f;
#pragma unroll
            for (int nt = 0; nt < 4; ++nt) { pv[nt] = __expf(pv[nt] - m); s += pv[nt]; }
            s += __shfl_xor(s, 1);
            s += __shfl_xor(s, 2);
            s += __shfl_xor(s, 4);
            s += __shfl_xor(s, 8);
            float inv = 1.f / s;
#pragma unroll
            for (int nt = 0; nt < 4; ++nt)
                Ps[qt * 72 + nt * 16 + (lane & 15)] = f2bf_bits(pv[nt] * inv);
        }
    }
    // no barrier: each wave reads only its own 16 Ps rows below (same-wave LDS dep,
    // ordered by lgkmcnt), and vT was consumed-ready at the load barrier.

    // O = P V : wave -> 16 rows x 32 dims, K=64 in 2 steps
    {
        f32x4 oacc[2] = {};
#pragma unroll
        for (int kstep = 0; kstep < 2; ++kstep) {
            const int kk = kstep * 32 + ((lane >> 4) << 3);
            short8 ap = *(const short8*)&Ps[(wave * 16 + (lane & 15)) * 72 + kk];
#pragma unroll
            for (int nt = 0; nt < 2; ++nt) {
                short8 bv = *(const short8*)&vT[(nt * 16 + (lane & 15)) * 72 + kk];
                oacc[nt] = __builtin_amdgcn_mfma_f32_16x16x32_bf16(ap, bv, oacc[nt], 0, 0, 0);
            }
        }
        short* og = (short*)qkv + base;  // overwrite q slice (disjoint per block)
#pragma unroll
        for (int nt = 0; nt < 2; ++nt)
#pragma unroll
            for (int reg = 0; reg < 4; ++reg) {
                int t = wave * 16 + ((lane >> 4) << 2) + reg;
                int d = nt * 16 + (lane & 15);
                og[t * 32 + d] = f2bf_bits(oacc[nt][reg]);
            }
    }
}

// ---------------- out projection GEMM: A = attn out (q slice), scatter fp32 with roll ----------------
// 1D grid 2048 with chunked XCD swizzle (same rationale as qkv_gemm).
__global__ __launch_bounds__(256, 4)
void out_gemm(const bf16* __restrict__ ain, const bf16* __restrict__ wT,
              const float* __restrict__ bout, float* __restrict__ out) {
    __shared__ __align__(16) short As[128 * 32];
    __shared__ __align__(16) short Bs[128 * 32];
    const int tid = threadIdx.x;
    const int lane = tid & 63, wave = tid >> 6;
    const int wr = wave >> 1, wc = wave & 1;
    const int h = blockIdx.x;
    const int v = (h & 7) * 256 + (h >> 3);   // bijective: 2048 % 8 == 0
    const int bx = v & 3, by = v >> 2;
    const int m0 = by * 128, n0 = bx * 128;

    const int lrow = lane >> 2, lc8 = (lane & 3) << 3;
    // A[r][k]: k = head*32+d -> ain[((win*16+head)*64 + t)*32 + d]; +k0 step = k0*64 elems
    const short* agA[2];
    const short* bgB[2];
    short* ldsA[2];
    short* ldsB[2];
#pragma unroll
    for (int s = 0; s < 2; ++s) {
        int c = wave + s * 4;
        int r = m0 + c * 16 + lrow, win = r >> 6, t = r & 63;
        agA[s] = (const short*)ain + win * 32768 + t * 32 + lc8;
        bgB[s] = (const short*)wT + (n0 + c * 16 + lrow) * 512 + lc8;
        ldsA[s] = As + c * 512;
        ldsB[s] = Bs + c * 512;
    }

    f32x4 acc[4][4] = {};
    for (int k0 = 0; k0 < 512; k0 += 32) {
        __syncthreads();
        GLOAD_LDS16(agA[0] + k0 * 64, ldsA[0]);
        GLOAD_LDS16(agA[1] + k0 * 64, ldsA[1]);
        GLOAD_LDS16(bgB[0] + k0, ldsB[0]);
        GLOAD_LDS16(bgB[1] + k0, ldsB[1]);
        __syncthreads();
        const int kk = (lane >> 4) << 3;
        short8 af[4], bfr[4];
#pragma unroll
        for (int mt = 0; mt < 4; ++mt)
            af[mt] = *(const short8*)&As[(wr * 64 + mt * 16 + (lane & 15)) * 32 + kk];
#pragma unroll
        for (int nt = 0; nt < 4; ++nt)
            bfr[nt] = *(const short8*)&Bs[(wc * 64 + nt * 16 + (lane & 15)) * 32 + kk];
#pragma unroll
        for (int mt = 0; mt < 4; ++mt)
#pragma unroll
            for (int nt = 0; nt < 4; ++nt)
                acc[mt][nt] = __builtin_amdgcn_mfma_f32_16x16x32_bf16(af[mt], bfr[nt],
                                                                      acc[mt][nt], 0, 0, 0);
    }

    // epilogue: pix(r0+reg) == pix(r0)+reg within the 4-row group (w stays multiple of 4 after wrap)
#pragma unroll
    for (int mt = 0; mt < 4; ++mt) {
        int r0 = m0 + wr * 64 + mt * 16 + ((lane >> 4) << 2);
        int pix0 = row_to_pixel(r0);
#pragma unroll
        for (int nt = 0; nt < 4; ++nt) {
            int c = n0 + wc * 64 + nt * 16 + (lane & 15);
            float bias = bout[c];
            float* po = out + pix0 * 512 + c;
#pragma unroll
            for (int reg = 0; reg < 4; ++reg)
                po[reg * 512] = acc[mt][nt][reg] + bias;
        }
    }
}

extern "C" void kernel_launch(void* const* d_in, const int* in_sizes, int n_in,
                              void* d_out, int out_size, void* d_ws, size_t ws_size,
                              hipStream_t stream) {
    const float* x       = (const float*)d_in[0];   // (16,64,64,512) fp32
    const float* w_qkv   = (const float*)d_in[1];   // (512,1536) fp32
    const float* b_qkv   = (const float*)d_in[2];   // (1536,) fp32
    const float* rel_pos = (const float*)d_in[3];   // (225,16) fp32
    const float* w_out   = (const float*)d_in[4];   // (512,512) fp32
    const float* b_out   = (const float*)d_in[5];   // (512,) fp32
    float* out = (float*)d_out;

    bf16* wqkvT  = (bf16*)d_ws;                  // 1536*512 bf16
    bf16* woutT  = wqkvT + 1536 * 512;           // 512*512 bf16
    bf16* qkvbuf = woutT + 512 * 512;            // 3*1024*16*64*32 bf16 (~201 MB)

    // A' (gathered bf16 x, 65536x512 = 67 MB) lives in d_out: it is fully
    // consumed by qkv_gemm before out_gemm overwrites d_out at the end.
    short* agather = (short*)d_out;

    transpose_f2b<<<(512 * 1536 + 255) / 256, 256, 0, stream>>>(
        w_qkv, (short*)wqkvT, 512, 1536);
    transpose_f2b<<<(512 * 512 + 255) / 256, 256, 0, stream>>>(
        w_out, (short*)woutT, 512, 512);
    gather_cast<<<16384, 256, 0, stream>>>(x, agather);
    qkv_gemm<<<6144, 256, 0, stream>>>((const bf16*)agather, wqkvT, b_qkv, qkvbuf);
    attn_kernel<<<dim3(1024, 16), 256, 0, stream>>>(qkvbuf, rel_pos);
    out_gemm<<<2048, 256, 0, stream>>>(qkvbuf, woutT, b_out, out);
}

// Round 7
// 484.492 us; speedup vs baseline: 1.0466x; 1.0026x over previous
//
#include <hip/hip_runtime.h>
#include <hip/hip_bf16.h>
#include <stdint.h>

typedef __hip_bfloat16 bf16;
typedef __attribute__((ext_vector_type(8))) short short8;
typedef __attribute__((ext_vector_type(4))) float f32x4;

#define NWIN 1024
#define NH 16
#define HD 32
#define SHIFT 4

// async global->LDS, 16B per lane; LDS dest is wave-uniform base + lane*16
#define GLOAD_LDS16(gptr, lptr)                                                      \
    __builtin_amdgcn_global_load_lds(                                                \
        (const __attribute__((address_space(1))) void*)(gptr),                       \
        (__attribute__((address_space(3))) void*)(lptr), 16, 0, 0)

// window row r (= win*64 + token) -> source/dest pixel index in (B,64,64) grid.
__device__ __forceinline__ int row_to_pixel(int r) {
    int win = r >> 6, t = r & 63;
    int b = win >> 6, wy = (win >> 3) & 7, wx = win & 7;
    int h = ((wy << 3) + (t >> 3) + SHIFT) & 63;
    int w = ((wx << 3) + (t & 7) + SHIFT) & 63;
    return (((b << 6) | h) << 6) | w;
}

__device__ __forceinline__ short f2bf_bits(float f) {
    bf16 h = __float2bfloat16(f);
    return *reinterpret_cast<short*>(&h);
}

// fp32 -> bf16 transpose for weights
__global__ void transpose_f2b(const float* __restrict__ src, short* __restrict__ dst,
                              int K, int N) {
    int idx = blockIdx.x * 256 + threadIdx.x;
    if (idx >= K * N) return;
    int k = idx / N, n = idx - k * N;
    dst[n * K + k] = f2bf_bits(src[idx]);
}

// ---------------- pre-pass: gather (cyclic roll + window partition) + fp32->bf16 cast ----------------
__global__ __launch_bounds__(256)
void gather_cast(const float* __restrict__ x, short* __restrict__ a) {
    int chunk = blockIdx.x * 256 + threadIdx.x;   // 65536*64 chunks of 8
    int r = chunk >> 6, c8 = (chunk & 63) << 3;
    int pix = row_to_pixel(r);
    const float* src = x + pix * 512 + c8;
    float4 f0 = *(const float4*)src;
    float4 f1 = *(const float4*)(src + 4);
    short8 v;
    v[0] = f2bf_bits(f0.x); v[1] = f2bf_bits(f0.y);
    v[2] = f2bf_bits(f0.z); v[3] = f2bf_bits(f0.w);
    v[4] = f2bf_bits(f1.x); v[5] = f2bf_bits(f1.y);
    v[6] = f2bf_bits(f1.z); v[7] = f2bf_bits(f1.w);
    *(short8*)(a + r * 512 + c8) = v;
}

// ---------------- QKV GEMM: A = pre-gathered bf16 (65536 x 512), B = wqkvT bf16 (1536 x 512) ----------------
// 256x256 tile, 8 waves (2M x 4N), BK=32, TRIPLE-buffered LDS, counted vmcnt(4)
// (never drains to 0 in steady state), raw s_barrier, XOR-swizzled LDS reads with
// inverse-permuted global_load_lds sources (rule #21), setprio around MFMA cluster.
// XCD chunked swizzle: each XCD owns 32 consecutive 256-row A-panels (x6 n-blocks).
__global__ __launch_bounds__(512, 1)
void qkv_gemm(const bf16* __restrict__ a, const bf16* __restrict__ wT,
              const float* __restrict__ bqkv, bf16* __restrict__ qkv) {
    // per K-tile: A 256x32 bf16 = 16KB (8192 shorts), B same; 3 buffers each.
    __shared__ __align__(16) short As[3 * 8192];
    __shared__ __align__(16) short Bs[3 * 8192];
    const int tid = threadIdx.x;
    const int lane = tid & 63, wave = tid >> 6;
    const int wm = wave >> 2, wn = wave & 3;      // 2M x 4N wave grid
    const int l15 = lane & 15;
    const int h = blockIdx.x;
    const int v = (h & 7) * 192 + (h >> 3);       // bijective: 1536 % 8 == 0
    const int by = v / 6, bx = v - by * 6;
    const int m0 = by * 256, n0 = bx * 256;

    // Staging: chunk c (0..15) = rows [16c,16c+16) x 32 shorts (64B/row) = 1KB.
    // lane l -> row 16c + (l>>2), 16B slot (l&3). Source slot pre-permuted by the
    // read-side XOR involution: ss = (l&3) ^ ((l>>2)&3).  (lin[r][s] = g[r][s^(r&3)])
    const int lr = lane >> 2;
    const int ss = (lane & 3) ^ (lr & 3);
    const short* agA0 = (const short*)a + (size_t)(m0 + wave * 16 + lr) * 512 + ss * 8;
    const short* bgB0 = (const short*)wT + (size_t)(n0 + wave * 16 + lr) * 512 + ss * 8;
    // read-side swizzled k-offset: slot = kq ^ (row&3), row&3 == lane&3 for frag rows
    const int koff = (((lane >> 4) ^ (lane & 3)) & 3) << 3;

#define QKV_STAGE(tt, b) do {                                                        \
        const short* _a0 = agA0 + (tt) * 32;                                         \
        const short* _b0 = bgB0 + (tt) * 32;                                         \
        GLOAD_LDS16(_a0,             &As[(b) * 8192 + wave * 512]);                  \
        GLOAD_LDS16(_a0 + 128 * 512, &As[(b) * 8192 + (wave + 8) * 512]);            \
        GLOAD_LDS16(_b0,             &Bs[(b) * 8192 + wave * 512]);                  \
        GLOAD_LDS16(_b0 + 128 * 512, &Bs[(b) * 8192 + (wave + 8) * 512]);            \
    } while (0)

    QKV_STAGE(0, 0);
    QKV_STAGE(1, 1);
    asm volatile("s_waitcnt vmcnt(4)" ::: "memory");   // tile 0 landed; tile 1 in flight
    __builtin_amdgcn_sched_barrier(0);
    __builtin_amdgcn_s_barrier();
    __builtin_amdgcn_sched_barrier(0);

    f32x4 acc[8][4] = {};
    int p = 0;
#pragma unroll
    for (int t = 0; t < 16; ++t) {
        if (t < 14) {
            int b2 = p + 2; if (b2 >= 3) b2 -= 3;
            QKV_STAGE(t + 2, b2);                      // 2 tiles ahead, never read this tile
        }
        const short* Ab = &As[p * 8192];
        const short* Bb = &Bs[p * 8192];
        short8 af[8], bv[4];
#pragma unroll
        for (int mt = 0; mt < 8; ++mt)
            af[mt] = *(const short8*)&Ab[(wm * 128 + mt * 16 + l15) * 32 + koff];
#pragma unroll
        for (int nt = 0; nt < 4; ++nt)
            bv[nt] = *(const short8*)&Bb[(wn * 64 + nt * 16 + l15) * 32 + koff];
        __builtin_amdgcn_s_setprio(1);
#pragma unroll
        for (int mt = 0; mt < 8; ++mt)
#pragma unroll
            for (int nt = 0; nt < 4; ++nt)
                acc[mt][nt] = __builtin_amdgcn_mfma_f32_16x16x32_bf16(af[mt], bv[nt],
                                                                      acc[mt][nt], 0, 0, 0);
        __builtin_amdgcn_s_setprio(0);
        // ledger: outstanding = tile t+1 (4, issued last iter) + tile t+2 (4, this iter);
        // vmcnt(4) -> t+1's retired, t+2's stay in flight across the barrier.
        if (t < 14)       asm volatile("s_waitcnt vmcnt(4)" ::: "memory");
        else if (t == 14) asm volatile("s_waitcnt vmcnt(0)" ::: "memory");
        if (t < 15) {
            __builtin_amdgcn_sched_barrier(0);
            __builtin_amdgcn_s_barrier();
            __builtin_amdgcn_sched_barrier(0);
        }
        p = (p == 2) ? 0 : p + 1;
    }
#undef QKV_STAGE

    // epilogue: C/D layout col=lane&15, row=(lane>>4)*4+reg [m89]
#pragma unroll
    for (int mt = 0; mt < 8; ++mt) {
        int r0 = m0 + wm * 128 + mt * 16 + ((lane >> 4) << 2);
        int win = r0 >> 6, t0 = r0 & 63;
#pragma unroll
        for (int nt = 0; nt < 4; ++nt) {
            int c = n0 + wn * 64 + nt * 16 + l15;
            int which = c >> 9, head = (c >> 5) & 15, d = c & 31;
            float bias = bqkv[c];
            float scale = (which == 0) ? 0.17677669529663689f : 1.0f;
            short* pq = (short*)qkv + (((which * NWIN + win) * NH + head) * 64 + t0) * HD + d;
#pragma unroll
            for (int reg = 0; reg < 4; ++reg)
                pq[reg * HD] = f2bf_bits((acc[mt][nt][reg] + bias) * scale);
        }
    }
}

// ---------------- attention: one block per (window, head) ----------------
// Softmax in MFMA C-layout (shfl_xor row-reduce); 1 barrier; 4 blocks/CU.
__global__ __launch_bounds__(256, 4)
void attn_kernel(bf16* __restrict__ qkv, const float* __restrict__ relpos) {
    const int win = blockIdx.x, head = blockIdx.y;
    __shared__ __align__(16) short qs[64 * 40];
    __shared__ __align__(16) short ks[64 * 40];
    __shared__ __align__(16) short vT[32 * 72];
    __shared__ __align__(16) short Ps[64 * 72];
    __shared__ float rel[225];
    const int tid = threadIdx.x, lane = tid & 63, wave = tid >> 6;
    const int base = (win * NH + head) * 2048;
    const short* qg = (const short*)qkv + base;
    const short* kg = qg + NWIN * NH * 2048;
    const short* vg = kg + NWIN * NH * 2048;

    {
        int row = tid >> 2, c8 = (tid & 3) << 3;
        *(short8*)&qs[row * 40 + c8] = *(const short8*)(qg + row * 32 + c8);
        *(short8*)&ks[row * 40 + c8] = *(const short8*)(kg + row * 32 + c8);
        short8 vv = *(const short8*)(vg + row * 32 + c8);
#pragma unroll
        for (int e = 0; e < 8; ++e) vT[(c8 + e) * 72 + row] = vv[e];
    }
    if (tid < 225) rel[tid] = relpos[tid * 16 + head];   // only this head's column
    __syncthreads();

    {
        const int kk = (lane >> 4) << 3;
        short8 aq = *(const short8*)&qs[(wave * 16 + (lane & 15)) * 40 + kk];
        f32x4 sacc[4];
#pragma unroll
        for (int nt = 0; nt < 4; ++nt) {
            short8 bk = *(const short8*)&ks[(nt * 16 + (lane & 15)) * 40 + kk];
            f32x4 z = {};
            sacc[nt] = __builtin_amdgcn_mfma_f32_16x16x32_bf16(aq, bk, z, 0, 0, 0);
        }
#pragma unroll
        for (int reg = 0; reg < 4; ++reg) {
            int qt = wave * 16 + ((lane >> 4) << 2) + reg;
            float pv[4];
            float m = -3e38f;
#pragma unroll
            for (int nt = 0; nt < 4; ++nt) {
                int kt = nt * 16 + (lane & 15);
                int idx = ((qt >> 3) - (kt >> 3) + 7) * 15 + ((qt & 7) - (kt & 7) + 7);
                pv[nt] = sacc[nt][reg] + rel[idx];
                m = fmaxf(m, pv[nt]);
            }
            m = fmaxf(m, __shfl_xor(m, 1));
            m = fmaxf(m, __shfl_xor(m, 2));
            m = fmaxf(m, __shfl_xor(m, 4));
            m = fmaxf(m, __shfl_xor(m, 8));
            float s = 0.f;
#pragma unroll
            for (int nt = 0; nt < 4; ++nt) { pv[nt] = __expf(pv[nt] - m); s += pv[nt]; }
            s += __shfl_xor(s, 1);
            s += __shfl_xor(s, 2);
            s += __shfl_xor(s, 4);
            s += __shfl_xor(s, 8);
            float inv = 1.f / s;
#pragma unroll
            for (int nt = 0; nt < 4; ++nt)
                Ps[qt * 72 + nt * 16 + (lane & 15)] = f2bf_bits(pv[nt] * inv);
        }
    }
    // no barrier: each wave reads only its own 16 Ps rows below (same-wave LDS dep).

    {
        f32x4 oacc[2] = {};
#pragma unroll
        for (int kstep = 0; kstep < 2; ++kstep) {
            const int kk = kstep * 32 + ((lane >> 4) << 3);
            short8 ap = *(const short8*)&Ps[(wave * 16 + (lane & 15)) * 72 + kk];
#pragma unroll
            for (int nt = 0; nt < 2; ++nt) {
                short8 bvv = *(const short8*)&vT[(nt * 16 + (lane & 15)) * 72 + kk];
                oacc[nt] = __builtin_amdgcn_mfma_f32_16x16x32_bf16(ap, bvv, oacc[nt], 0, 0, 0);
            }
        }
        short* og = (short*)qkv + base;  // overwrite q slice (disjoint per block)
#pragma unroll
        for (int nt = 0; nt < 2; ++nt)
#pragma unroll
            for (int reg = 0; reg < 4; ++reg) {
                int t = wave * 16 + ((lane >> 4) << 2) + reg;
                int d = nt * 16 + (lane & 15);
                og[t * 32 + d] = f2bf_bits(oacc[nt][reg]);
            }
    }
}

// ---------------- out projection GEMM: A = attn out (q slice), scatter fp32 with roll ----------------
__global__ __launch_bounds__(256, 4)
void out_gemm(const bf16* __restrict__ ain, const bf16* __restrict__ wT,
              const float* __restrict__ bout, float* __restrict__ out) {
    __shared__ __align__(16) short As[128 * 32];
    __shared__ __align__(16) short Bs[128 * 32];
    const int tid = threadIdx.x;
    const int lane = tid & 63, wave = tid >> 6;
    const int wr = wave >> 1, wc = wave & 1;
    const int h = blockIdx.x;
    const int v = (h & 7) * 256 + (h >> 3);   // bijective: 2048 % 8 == 0
    const int bx = v & 3, by = v >> 2;
    const int m0 = by * 128, n0 = bx * 128;

    const int lrow = lane >> 2, lc8 = (lane & 3) << 3;
    const short* agA[2];
    const short* bgB[2];
    short* ldsA[2];
    short* ldsB[2];
#pragma unroll
    for (int s = 0; s < 2; ++s) {
        int c = wave + s * 4;
        int r = m0 + c * 16 + lrow, win = r >> 6, t = r & 63;
        agA[s] = (const short*)ain + win * 32768 + t * 32 + lc8;
        bgB[s] = (const short*)wT + (n0 + c * 16 + lrow) * 512 + lc8;
        ldsA[s] = As + c * 512;
        ldsB[s] = Bs + c * 512;
    }

    f32x4 acc[4][4] = {};
    for (int k0 = 0; k0 < 512; k0 += 32) {
        __syncthreads();
        GLOAD_LDS16(agA[0] + k0 * 64, ldsA[0]);
        GLOAD_LDS16(agA[1] + k0 * 64, ldsA[1]);
        GLOAD_LDS16(bgB[0] + k0, ldsB[0]);
        GLOAD_LDS16(bgB[1] + k0, ldsB[1]);
        __syncthreads();
        const int kk = (lane >> 4) << 3;
        short8 af[4], bfr[4];
#pragma unroll
        for (int mt = 0; mt < 4; ++mt)
            af[mt] = *(const short8*)&As[(wr * 64 + mt * 16 + (lane & 15)) * 32 + kk];
#pragma unroll
        for (int nt = 0; nt < 4; ++nt)
            bfr[nt] = *(const short8*)&Bs[(wc * 64 + nt * 16 + (lane & 15)) * 32 + kk];
#pragma unroll
        for (int mt = 0; mt < 4; ++mt)
#pragma unroll
            for (int nt = 0; nt < 4; ++nt)
                acc[mt][nt] = __builtin_amdgcn_mfma_f32_16x16x32_bf16(af[mt], bfr[nt],
                                                                      acc[mt][nt], 0, 0, 0);
    }

#pragma unroll
    for (int mt = 0; mt < 4; ++mt) {
        int r0 = m0 + wr * 64 + mt * 16 + ((lane >> 4) << 2);
        int pix0 = row_to_pixel(r0);
#pragma unroll
        for (int nt = 0; nt < 4; ++nt) {
            int c = n0 + wc * 64 + nt * 16 + (lane & 15);
            float bias = bout[c];
            float* po = out + pix0 * 512 + c;
#pragma unroll
            for (int reg = 0; reg < 4; ++reg)
                po[reg * 512] = acc[mt][nt][reg] + bias;
        }
    }
}

extern "C" void kernel_launch(void* const* d_in, const int* in_sizes, int n_in,
                              void* d_out, int out_size, void* d_ws, size_t ws_size,
                              hipStream_t stream) {
    const float* x       = (const float*)d_in[0];   // (16,64,64,512) fp32
    const float* w_qkv   = (const float*)d_in[1];   // (512,1536) fp32
    const float* b_qkv   = (const float*)d_in[2];   // (1536,) fp32
    const float* rel_pos = (const float*)d_in[3];   // (225,16) fp32
    const float* w_out   = (const float*)d_in[4];   // (512,512) fp32
    const float* b_out   = (const float*)d_in[5];   // (512,) fp32
    float* out = (float*)d_out;

    bf16* wqkvT  = (bf16*)d_ws;                  // 1536*512 bf16
    bf16* woutT  = wqkvT + 1536 * 512;           // 512*512 bf16
    bf16* qkvbuf = woutT + 512 * 512;            // 3*1024*16*64*32 bf16 (~201 MB)

    // A' (gathered bf16 x, 65536x512 = 67 MB) lives in d_out: fully consumed by
    // qkv_gemm before out_gemm overwrites d_out at the end.
    short* agather = (short*)d_out;

    transpose_f2b<<<(512 * 1536 + 255) / 256, 256, 0, stream>>>(
        w_qkv, (short*)wqkvT, 512, 1536);
    transpose_f2b<<<(512 * 512 + 255) / 256, 256, 0, stream>>>(
        w_out, (short*)woutT, 512, 512);
    gather_cast<<<16384, 256, 0, stream>>>(x, agather);
    qkv_gemm<<<1536, 512, 0, stream>>>((const bf16*)agather, wqkvT, b_qkv, qkvbuf);
    attn_kernel<<<dim3(1024, 16), 256, 0, stream>>>(qkvbuf, rel_pos);
    out_gemm<<<2048, 256, 0, stream>>>(qkvbuf, woutT, b_out, out);
}